// Round 2
// baseline (596.478 us; speedup 1.0000x reference)
//
#include <hip/hip_runtime.h>
#include <hip/hip_bf16.h>

// TLSTM forecaster, persistent-block design.
// B=4096, L=64, D=16, H=128, NL=2, FUT*MD=60, HEAD_IN=144.
// grid=256 blocks x 256 thr; each block owns 16 batch rows for all 64 steps.
// Gate order in packed weights: [i, o, c]  (reference's f-gate is dead code).
//
// MFMA 16x16x32 bf16 layouts (per cdna docs, m89/m91-verified C/D):
//   A[m=lane&15][k=(lane>>4)*8+j]   (8 contiguous bf16 -> one b128 LDS read)
//   B[k=(lane>>4)*8+j][n=lane&15]   (weights packed transposed: BT[n][k] row-major)
//   D[row=(lane>>4)*4+r][col=lane&15]

typedef __bf16 bf16x8 __attribute__((ext_vector_type(8)));
typedef float  f32x4  __attribute__((ext_vector_type(4)));

__device__ __forceinline__ f32x4 mfma16(bf16x8 a, bf16x8 b, f32x4 c) {
  return __builtin_amdgcn_mfma_f32_16x16x32_bf16(a, b, c, 0, 0, 0);
}
__device__ __forceinline__ float sigmf(float x) {
  return __fdividef(1.f, 1.f + __expf(-x));
}
__device__ __forceinline__ float tanhfast(float x) {
  // 1 - 2/(1+e^{2x}); correct limits at +-inf with fast div
  return 1.f - __fdividef(2.f, 1.f + __expf(2.f * x));
}

// ---------------- ws layout (bytes) ----------------
// BT0  : [384][160] bf16  @ 0        (k 0..15 = Wp@Wx0 fold, 16..31 = zeros, 32..159 = Uh0)
// BWd0 : [128][128] bf16  @ 122880
// BT1  : [384][256] bf16  @ 155648   (k 0..127 = Wx1, 128..255 = Uh1)
// BWd1 : [128][128] bf16  @ 352256
// bz0  : [384] f32        @ 385024   (bp@Wx0 fold + bx0)
#define OFF_BWD0 122880
#define OFF_BT1  155648
#define OFF_BWD1 352256
#define OFF_BZ0  385024

// Prologue 1: fold Wp@Wx0 (K=16 block of layer-0 B) + folded bias. idx = n*17+kk.
__global__ void tlstm_fold(const float* __restrict__ Wp, const float* __restrict__ bp,
                           const float* __restrict__ Wx, const float* __restrict__ bx,
                           __bf16* __restrict__ BT0, float* __restrict__ bz0) {
  int idx = blockIdx.x * 256 + threadIdx.x;
  if (idx >= 384 * 17) return;
  int n = idx / 17, kk = idx % 17;
  int g = n >> 7, npr = n & 127, gs = g + 1;               // src gates 1,2,3 = i,o,c
  const float* wxcol = Wx + (gs * 128) * 128 + npr;        // Wx[0][gs][h][npr], stride 128
  if (kk < 16) {
    const float* wprow = Wp + kk * 128;
    float s = 0.f;
    for (int h = 0; h < 128; ++h) s += wprow[h] * wxcol[h * 128];
    BT0[n * 160 + kk] = (__bf16)s;
  } else {
    float s = bx[gs * 128 + npr];
    for (int h = 0; h < 128; ++h) s += bp[h] * wxcol[h * 128];
    bz0[n] = s;
    for (int k2 = 16; k2 < 32; ++k2) BT0[n * 160 + k2] = (__bf16)0.f;  // zero K-pad
  }
}

// Prologue 2: transpose-pack remaining weights to bf16 BT layouts. 180224 elems.
__global__ void tlstm_pack(const float* __restrict__ Wx, const float* __restrict__ Uh,
                           const float* __restrict__ Wd,
                           __bf16* __restrict__ BT0, __bf16* __restrict__ BWd0,
                           __bf16* __restrict__ BT1, __bf16* __restrict__ BWd1) {
  int e = blockIdx.x * 256 + threadIdx.x;
  if (e < 49152) {                                  // BT0 Uh0 region
    int n = e >> 7, k = e & 127, g = n >> 7, npr = n & 127, gs = g + 1;
    BT0[n * 160 + 32 + k] = (__bf16)Uh[(gs * 128 + k) * 128 + npr];
  } else if (e < 65536) {                           // BWd0
    int e2 = e - 49152; int n = e2 >> 7, k = e2 & 127;
    BWd0[n * 128 + k] = (__bf16)Wd[k * 128 + n];
  } else if (e < 163840) {                          // BT1 = [Wx1 ; Uh1]
    int e2 = e - 65536; int n = e2 >> 8, k = e2 & 255;
    int g = n >> 7, npr = n & 127, gs = g + 1;
    float v = (k < 128) ? Wx[((4 + gs) * 128 + k) * 128 + npr]
                        : Uh[((4 + gs) * 128 + (k - 128)) * 128 + npr];
    BT1[n * 256 + k] = (__bf16)v;
  } else if (e < 180224) {                          // BWd1
    int e2 = e - 163840; int n = e2 >> 7, k = e2 & 127;
    BWd1[n * 128 + k] = (__bf16)Wd[(128 + k) * 128 + n];
  }
}

__global__ __launch_bounds__(256, 1) void tlstm_main(
    const float* __restrict__ hist, const float* __restrict__ hmask,
    const __bf16* __restrict__ BT0, const __bf16* __restrict__ BWd0,
    const __bf16* __restrict__ BT1, const __bf16* __restrict__ BWd1,
    const float* __restrict__ bz0, const float* __restrict__ bx,
    const float* __restrict__ bd, const float* __restrict__ Wt,
    const float* __restrict__ bt, const float* __restrict__ lng,
    const float* __restrict__ lnb, const float* __restrict__ W1,
    const float* __restrict__ b1, const float* __restrict__ W2,
    const float* __restrict__ b2, float* __restrict__ out) {
  __shared__ __align__(16) __bf16 A0[16][160];   // [hist16 | zero16 | h0:128]
  __shared__ __align__(16) __bf16 A1[16][256];   // [h0_new:128 | h1:128]
  __shared__ __align__(16) __bf16 Atmp[16][128]; // h_tilde staging for Wd GEMMs
  __shared__ float decayL[16];
  __shared__ float maskL[16];
  __shared__ int   lastL[16];
  __shared__ float stateL[16][144];
  __shared__ float a1L[16][128];
  __shared__ float redS[16][16];
  __shared__ float redQ[16][16];

  const int tid  = threadIdx.x;
  const int wave = tid >> 6;
  const int lane = tid & 63;
  const int q    = lane >> 4;
  const int c16  = lane & 15;
  const int q8   = q * 8;
  const int b0   = blockIdx.x * 16;

  // ---- init ----
  if (tid < 16) {
    float s = 0.f;
    for (int t = 0; t < 64; ++t) s += hmask[(b0 + tid) * 64 + t];
    s = fminf(fmaxf(s, 1.f), 64.f);
    lastL[tid] = (int)s - 1;
  }
  for (int i = tid; i < 16 * 144; i += 256) {
    int r = i / 144, c = i % 144;
    A0[r][16 + c] = (__bf16)0.f;       // zero-pad + h0 init
  }
  for (int i = tid; i < 16 * 256; i += 256) {
    A1[i >> 8][i & 255] = (__bf16)0.f; // h0_new slot + h1 init
  }

  // per-lane column constants (each wave owns cols [32w,32w+32), tt=0/1 halves)
  const int np0 = wave * 32 + c16;
  const int np1 = np0 + 16;
  float bz0r[3][2], bz1r[3][2];
#pragma unroll
  for (int g = 0; g < 3; ++g) {
    bz0r[g][0] = bz0[g * 128 + np0];        bz0r[g][1] = bz0[g * 128 + np1];
    bz1r[g][0] = bx[(5 + g) * 128 + np0];   bz1r[g][1] = bx[(5 + g) * 128 + np1];
  }
  float bd0r[2] = { bd[np0],        bd[np1] };
  float bd1r[2] = { bd[128 + np0],  bd[128 + np1] };
  float wt0r[2] = { Wt[np0],        Wt[np1] };
  float wt1r[2] = { Wt[128 + np0],  Wt[128 + np1] };
  float bt0r[2] = { bt[np0],        bt[np1] };
  float bt1r[2] = { bt[128 + np0],  bt[128 + np1] };

  int offZ0[6], offZ1[6];
#pragma unroll
  for (int g = 0; g < 3; ++g) {
    offZ0[g * 2 + 0] = (g * 128 + np0) * 160 + q8;
    offZ0[g * 2 + 1] = (g * 128 + np1) * 160 + q8;
    offZ1[g * 2 + 0] = (g * 128 + np0) * 256 + q8;
    offZ1[g * 2 + 1] = (g * 128 + np1) * 256 + q8;
  }
  const int offD[2] = { np0 * 128 + q8, np1 * 128 + q8 };

  float h0r[2][4] = {}, c0r[2][4] = {}, h1r[2][4] = {}, c1r[2][4] = {}, encr[2][4] = {};
  const f32x4 zero4 = { 0.f, 0.f, 0.f, 0.f };

  __syncthreads();

  int lrow[4];
#pragma unroll
  for (int r = 0; r < 4; ++r) lrow[r] = lastL[q * 4 + r];

  const int srow = tid >> 4, scol = tid & 15;
  const float* histrow = hist + (long)(b0 + srow) * 1024 + scol;

  for (int t = 0; t < 64; ++t) {
    // ---- stage hist features, decay, mask ----
    {
      float v = histrow[t * 16];
      A0[srow][scol] = (__bf16)v;
      if (scol == 5)
        decayL[srow] = __fdividef(1.f, __logf(2.7182818284590452f + fmaxf(v, 0.f)));
      if (scol == 0) maskL[srow] = hmask[(b0 + srow) * 64 + t];
    }
    __syncthreads();   // (1)

    float drow[4], mrow[4];
#pragma unroll
    for (int r = 0; r < 4; ++r) { drow[r] = decayL[q * 4 + r]; mrow[r] = maskL[q * 4 + r]; }

    // ---- layer 0: z = [hist|0|h0] @ [Wfold;0;Uh0] (K=160) ----
    f32x4 acc[6];
#pragma unroll
    for (int i = 0; i < 6; ++i) acc[i] = zero4;
#pragma unroll
    for (int kk = 0; kk < 5; ++kk) {
      bf16x8 a = *(const bf16x8*)&A0[c16][kk * 32 + q8];
#pragma unroll
      for (int i = 0; i < 6; ++i) {
        bf16x8 b = *(const bf16x8*)(BT0 + offZ0[i] + kk * 32);
        acc[i] = mfma16(a, b, acc[i]);
      }
    }
    float htl[2][4], otl[2][4];
#pragma unroll
    for (int tt = 0; tt < 2; ++tt) {
      const int col = tt ? np1 : np0;
#pragma unroll
      for (int r = 0; r < 4; ++r) {
        float zi = acc[0 + tt][r] + bz0r[0][tt];
        float zo = acc[2 + tt][r] + bz0r[1][tt];
        float zc = acc[4 + tt][r] + bz0r[2][tt];
        float ht = tanhfast(zc) + sigmf(zi);
        htl[tt][r] = ht;
        otl[tt][r] = sigmf(zo);
        Atmp[q * 4 + r][col] = (__bf16)ht;
      }
    }
    __syncthreads();   // (2)

    // ---- layer 0: h_short = tanh(h_tilde @ Wd0 + bd0), state update ----
    f32x4 accd[2] = { zero4, zero4 };
#pragma unroll
    for (int kk = 0; kk < 4; ++kk) {
      bf16x8 a = *(const bf16x8*)&Atmp[c16][kk * 32 + q8];
#pragma unroll
      for (int tt = 0; tt < 2; ++tt) {
        bf16x8 b = *(const bf16x8*)(BWd0 + offD[tt] + kk * 32);
        accd[tt] = mfma16(a, b, accd[tt]);
      }
    }
#pragma unroll
    for (int tt = 0; tt < 2; ++tt) {
      const int col = tt ? np1 : np0;
#pragma unroll
      for (int r = 0; r < 4; ++r) {
        float hs    = tanhfast(accd[tt][r] + bd0r[tt]);
        float dgate = sigmf(drow[r] * wt0r[tt] + bt0r[tt]);
        float hstar = htl[tt][r] + hs * (dgate - 1.f);
        float cn    = tanhfast(hstar + otl[tt][r] * c0r[tt][r]);
        float hn    = otl[tt][r] * tanhfast(cn);
        float m     = mrow[r];
        float hl    = m * hn + (1.f - m) * h0r[tt][r];
        float cl    = m * cn + (1.f - m) * c0r[tt][r];
        h0r[tt][r] = hl; c0r[tt][r] = cl;
        __bf16 hb = (__bf16)hl;
        int row = q * 4 + r;
        A0[row][32 + col] = hb;   // next step's layer-0 recurrent input
        A1[row][col]      = hb;   // this step's layer-1 feed-forward input
      }
    }
    __syncthreads();   // (3)

    // ---- layer 1: z = [h0_new|h1] @ [Wx1;Uh1] (K=256) ----
#pragma unroll
    for (int i = 0; i < 6; ++i) acc[i] = zero4;
#pragma unroll
    for (int kk = 0; kk < 8; ++kk) {
      bf16x8 a = *(const bf16x8*)&A1[c16][kk * 32 + q8];
#pragma unroll
      for (int i = 0; i < 6; ++i) {
        bf16x8 b = *(const bf16x8*)(BT1 + offZ1[i] + kk * 32);
        acc[i] = mfma16(a, b, acc[i]);
      }
    }
#pragma unroll
    for (int tt = 0; tt < 2; ++tt) {
      const int col = tt ? np1 : np0;
#pragma unroll
      for (int r = 0; r < 4; ++r) {
        float zi = acc[0 + tt][r] + bz1r[0][tt];
        float zo = acc[2 + tt][r] + bz1r[1][tt];
        float zc = acc[4 + tt][r] + bz1r[2][tt];
        float ht = tanhfast(zc) + sigmf(zi);
        htl[tt][r] = ht;
        otl[tt][r] = sigmf(zo);
        Atmp[q * 4 + r][col] = (__bf16)ht;
      }
    }
    __syncthreads();   // (4)

    // ---- layer 1: Wd1 + state update + capture encoded at t==last ----
    accd[0] = zero4; accd[1] = zero4;
#pragma unroll
    for (int kk = 0; kk < 4; ++kk) {
      bf16x8 a = *(const bf16x8*)&Atmp[c16][kk * 32 + q8];
#pragma unroll
      for (int tt = 0; tt < 2; ++tt) {
        bf16x8 b = *(const bf16x8*)(BWd1 + offD[tt] + kk * 32);
        accd[tt] = mfma16(a, b, accd[tt]);
      }
    }
#pragma unroll
    for (int tt = 0; tt < 2; ++tt) {
      const int col = tt ? np1 : np0;
#pragma unroll
      for (int r = 0; r < 4; ++r) {
        float hs    = tanhfast(accd[tt][r] + bd1r[tt]);
        float dgate = sigmf(drow[r] * wt1r[tt] + bt1r[tt]);
        float hstar = htl[tt][r] + hs * (dgate - 1.f);
        float cn    = tanhfast(hstar + otl[tt][r] * c1r[tt][r]);
        float hn    = otl[tt][r] * tanhfast(cn);
        float m     = mrow[r];
        float hl    = m * hn + (1.f - m) * h1r[tt][r];
        float cl    = m * cn + (1.f - m) * c1r[tt][r];
        h1r[tt][r] = hl; c1r[tt][r] = cl;
        A1[q * 4 + r][128 + col] = (__bf16)hl;
        if (t == lrow[r]) encr[tt][r] = hl * m;   // encoded = h1_l * mask
      }
    }
    // no barrier here: next iter's writes are barrier-separated from all readers
  }

  __syncthreads();

  // ---- decoder head: state = [hist[b,last,:16] | enc128]; LN; FC-ReLU-FC ----
  stateL[srow][scol] = hist[((long)(b0 + srow) * 64 + lastL[srow]) * 16 + scol];
#pragma unroll
  for (int tt = 0; tt < 2; ++tt)
#pragma unroll
    for (int r = 0; r < 4; ++r)
      stateL[q * 4 + r][16 + (tt ? np1 : np0)] = encr[tt][r];
  __syncthreads();

  {
    float sm = 0.f, sq = 0.f;
    for (int k = scol; k < 144; k += 16) {
      float v = stateL[srow][k];
      sm += v; sq += v * v;
    }
    redS[srow][scol] = sm; redQ[srow][scol] = sq;
  }
  __syncthreads();
  if (tid < 16) {
    float sm = 0.f, sq = 0.f;
    for (int s2 = 0; s2 < 16; ++s2) { sm += redS[tid][s2]; sq += redQ[tid][s2]; }
    float mu  = sm * (1.f / 144.f);
    float var = sq * (1.f / 144.f) - mu * mu;
    decayL[tid] = mu;                       // reuse buffers: mu
    maskL[tid]  = rsqrtf(var + 1e-5f);      // rstd
  }
  __syncthreads();
  {
    float mu = decayL[srow], rs = maskL[srow];
    for (int k = scol; k < 144; k += 16)
      stateL[srow][k] = (stateL[srow][k] - mu) * rs * lng[k] + lnb[k];
  }
  __syncthreads();
  {
    float accw[8];
#pragma unroll
    for (int o = 0; o < 8; ++o) accw[o] = b1[scol + 16 * o];
    for (int k = 0; k < 144; ++k) {
      float sv = stateL[srow][k];
      const float* w = W1 + k * 128 + scol;
#pragma unroll
      for (int o = 0; o < 8; ++o) accw[o] += sv * w[16 * o];
    }
#pragma unroll
    for (int o = 0; o < 8; ++o) a1L[srow][scol + 16 * o] = fmaxf(accw[o], 0.f);
  }
  __syncthreads();
  // FC2: 16 rows x 60 cols = 960 outputs per block, block-stride over 256 threads.
  for (int e = tid; e < 960; e += 256) {
    int row = e / 60, j = e - row * 60;
    float accv = b2[j];
    for (int k = 0; k < 128; ++k) accv += a1L[row][k] * W2[k * 60 + j];
    accv = (accv != accv) ? 0.f : fminf(fmaxf(accv, -1e4f), 1e4f);  // nan_to_num
    out[(b0 + row) * 60 + j] = accv;
  }
}

extern "C" void kernel_launch(void* const* d_in, const int* in_sizes, int n_in,
                              void* d_out, int out_size, void* d_ws, size_t ws_size,
                              hipStream_t stream) {
  const float* hist  = (const float*)d_in[0];
  const float* hmask = (const float*)d_in[1];
  const float* Wp    = (const float*)d_in[2];
  const float* bp    = (const float*)d_in[3];
  const float* Wx    = (const float*)d_in[4];
  const float* bx    = (const float*)d_in[5];
  const float* Uh    = (const float*)d_in[6];
  const float* Wd    = (const float*)d_in[7];
  const float* bd    = (const float*)d_in[8];
  const float* Wt    = (const float*)d_in[9];
  const float* bt    = (const float*)d_in[10];
  const float* lng   = (const float*)d_in[11];
  const float* lnb   = (const float*)d_in[12];
  const float* W1    = (const float*)d_in[13];
  const float* b1    = (const float*)d_in[14];
  const float* W2    = (const float*)d_in[15];
  const float* b2    = (const float*)d_in[16];
  float* out = (float*)d_out;

  char* ws = (char*)d_ws;
  __bf16* BT0  = (__bf16*)ws;
  __bf16* BWd0 = (__bf16*)(ws + OFF_BWD0);
  __bf16* BT1  = (__bf16*)(ws + OFF_BT1);
  __bf16* BWd1 = (__bf16*)(ws + OFF_BWD1);
  float*  bz0  = (float*)(ws + OFF_BZ0);

  tlstm_fold<<<26, 256, 0, stream>>>(Wp, bp, Wx, bx, BT0, bz0);
  tlstm_pack<<<704, 256, 0, stream>>>(Wx, Uh, Wd, BT0, BWd0, BT1, BWd1);
  tlstm_main<<<256, 256, 0, stream>>>(hist, hmask, BT0, BWd0, BT1, BWd1, bz0, bx,
                                      bd, Wt, bt, lng, lnb, W1, b1, W2, b2, out);
}

// Round 3
// 529.675 us; speedup vs baseline: 1.1261x; 1.1261x over previous
//
#include <hip/hip_runtime.h>
#include <hip/hip_bf16.h>

// TLSTM forecaster, persistent-block design. R3: 512 thr (8 waves), each wave
// owns 16 N-cols; LDS strides padded for conflict-free b128 reads; Wd weights
// hoisted to registers.
// B=4096, L=64, D=16, H=128, NL=2, FUT*MD=60, HEAD_IN=144.
// grid=256 blocks; each block owns 16 batch rows for all 64 steps.
// Gate order in packed weights: [i, o, c]  (reference's f-gate is dead code).
//
// MFMA 16x16x32 bf16 layouts:
//   A[m=lane&15][k=(lane>>4)*8+j]   (8 contiguous bf16 -> one b128 LDS read)
//   B[k=(lane>>4)*8+j][n=lane&15]   (weights packed transposed: BT[n][k] row-major)
//   D[row=(lane>>4)*4+r][col=lane&15]
//
// LDS pad: row strides 168/264/136 bf16 = 84/132/68 dw -> row-base banks are
// distinct multiples of 4 (period 8), giving uniform 8 dword-accesses/bank for
// the wave64 b128 A-reads (zero excess conflicts).

typedef __bf16 bf16x8 __attribute__((ext_vector_type(8)));
typedef float  f32x4  __attribute__((ext_vector_type(4)));

__device__ __forceinline__ f32x4 mfma16(bf16x8 a, bf16x8 b, f32x4 c) {
  return __builtin_amdgcn_mfma_f32_16x16x32_bf16(a, b, c, 0, 0, 0);
}
__device__ __forceinline__ float sigmf(float x) {
  return __fdividef(1.f, 1.f + __expf(-x));
}
__device__ __forceinline__ float tanhfast(float x) {
  return 1.f - __fdividef(2.f, 1.f + __expf(2.f * x));
}

// ---------------- ws layout (bytes) ----------------
// BT0  : [384][160] bf16  @ 0        (k 0..15 = Wp@Wx0 fold, 16..31 = zeros, 32..159 = Uh0)
// BWd0 : [128][128] bf16  @ 122880
// BT1  : [384][256] bf16  @ 155648   (k 0..127 = Wx1, 128..255 = Uh1)
// BWd1 : [128][128] bf16  @ 352256
// bz0  : [384] f32        @ 385024   (bp@Wx0 fold + bx0)
#define OFF_BWD0 122880
#define OFF_BT1  155648
#define OFF_BWD1 352256
#define OFF_BZ0  385024

__global__ void tlstm_fold(const float* __restrict__ Wp, const float* __restrict__ bp,
                           const float* __restrict__ Wx, const float* __restrict__ bx,
                           __bf16* __restrict__ BT0, float* __restrict__ bz0) {
  int idx = blockIdx.x * 256 + threadIdx.x;
  if (idx >= 384 * 17) return;
  int n = idx / 17, kk = idx % 17;
  int g = n >> 7, npr = n & 127, gs = g + 1;               // src gates 1,2,3 = i,o,c
  const float* wxcol = Wx + (gs * 128) * 128 + npr;        // Wx[0][gs][h][npr], stride 128
  if (kk < 16) {
    const float* wprow = Wp + kk * 128;
    float s = 0.f;
    for (int h = 0; h < 128; ++h) s += wprow[h] * wxcol[h * 128];
    BT0[n * 160 + kk] = (__bf16)s;
  } else {
    float s = bx[gs * 128 + npr];
    for (int h = 0; h < 128; ++h) s += bp[h] * wxcol[h * 128];
    bz0[n] = s;
    for (int k2 = 16; k2 < 32; ++k2) BT0[n * 160 + k2] = (__bf16)0.f;  // zero K-pad
  }
}

__global__ void tlstm_pack(const float* __restrict__ Wx, const float* __restrict__ Uh,
                           const float* __restrict__ Wd,
                           __bf16* __restrict__ BT0, __bf16* __restrict__ BWd0,
                           __bf16* __restrict__ BT1, __bf16* __restrict__ BWd1) {
  int e = blockIdx.x * 256 + threadIdx.x;
  if (e < 49152) {                                  // BT0 Uh0 region
    int n = e >> 7, k = e & 127, g = n >> 7, npr = n & 127, gs = g + 1;
    BT0[n * 160 + 32 + k] = (__bf16)Uh[(gs * 128 + k) * 128 + npr];
  } else if (e < 65536) {                           // BWd0
    int e2 = e - 49152; int n = e2 >> 7, k = e2 & 127;
    BWd0[n * 128 + k] = (__bf16)Wd[k * 128 + n];
  } else if (e < 163840) {                          // BT1 = [Wx1 ; Uh1]
    int e2 = e - 65536; int n = e2 >> 8, k = e2 & 255;
    int g = n >> 7, npr = n & 127, gs = g + 1;
    float v = (k < 128) ? Wx[((4 + gs) * 128 + k) * 128 + npr]
                        : Uh[((4 + gs) * 128 + (k - 128)) * 128 + npr];
    BT1[n * 256 + k] = (__bf16)v;
  } else if (e < 180224) {                          // BWd1
    int e2 = e - 163840; int n = e2 >> 7, k = e2 & 127;
    BWd1[n * 128 + k] = (__bf16)Wd[(128 + k) * 128 + n];
  }
}

__global__ __launch_bounds__(512, 2) void tlstm_main(
    const float* __restrict__ hist, const float* __restrict__ hmask,
    const __bf16* __restrict__ BT0, const __bf16* __restrict__ BWd0,
    const __bf16* __restrict__ BT1, const __bf16* __restrict__ BWd1,
    const float* __restrict__ bz0, const float* __restrict__ bx,
    const float* __restrict__ bd, const float* __restrict__ Wt,
    const float* __restrict__ bt, const float* __restrict__ lng,
    const float* __restrict__ lnb, const float* __restrict__ W1,
    const float* __restrict__ b1, const float* __restrict__ W2,
    const float* __restrict__ b2, float* __restrict__ out) {
  __shared__ __align__(16) __bf16 A0[16][168];   // [hist16 | zero16 | h0:128 | pad]
  __shared__ __align__(16) __bf16 A1[16][264];   // [h0_new:128 | h1:128 | pad]
  __shared__ __align__(16) __bf16 Atmp[16][136]; // h_tilde staging, pad
  __shared__ float decayL[16];
  __shared__ float maskL[16];
  __shared__ int   lastL[16];
  __shared__ float stateL[16][144];
  __shared__ float a1L[16][128];
  __shared__ float redS[16][16];
  __shared__ float redQ[16][16];

  const int tid  = threadIdx.x;
  const int wave = tid >> 6;         // 0..7
  const int lane = tid & 63;
  const int q    = lane >> 4;
  const int c16  = lane & 15;
  const int q8   = q * 8;
  const int b0   = blockIdx.x * 16;
  const int nc   = wave * 16 + c16;  // this wave's owned N-column (0..127)

  // ---- init ----
  if (tid < 16) {
    float s = 0.f;
    for (int t = 0; t < 64; ++t) s += hmask[(b0 + tid) * 64 + t];
    s = fminf(fmaxf(s, 1.f), 64.f);
    lastL[tid] = (int)s - 1;
  }
  for (int i = tid; i < 16 * 168; i += 512) (&A0[0][0])[i] = (__bf16)0.f;
  for (int i = tid; i < 16 * 264; i += 512) (&A1[0][0])[i] = (__bf16)0.f;

  // per-wave column constants
  float bz0r[3], bz1r[3];
#pragma unroll
  for (int g = 0; g < 3; ++g) {
    bz0r[g] = bz0[g * 128 + nc];
    bz1r[g] = bx[(5 + g) * 128 + nc];
  }
  const float bd0r = bd[nc],       bd1r = bd[128 + nc];
  const float wt0r = Wt[nc],       wt1r = Wt[128 + nc];
  const float bt0r = bt[nc],       bt1r = bt[128 + nc];

  int offZ0[3], offZ1[3];
#pragma unroll
  for (int g = 0; g < 3; ++g) {
    offZ0[g] = (g * 128 + nc) * 160 + q8;
    offZ1[g] = (g * 128 + nc) * 256 + q8;
  }

  // hoist Wd B-fragments into registers (uniform over t)
  bf16x8 bwd0[4], bwd1[4];
#pragma unroll
  for (int kk = 0; kk < 4; ++kk) {
    bwd0[kk] = *(const bf16x8*)(BWd0 + nc * 128 + q8 + kk * 32);
    bwd1[kk] = *(const bf16x8*)(BWd1 + nc * 128 + q8 + kk * 32);
  }

  float h0r[4] = {}, c0r[4] = {}, h1r[4] = {}, c1r[4] = {}, encr[4] = {};
  const f32x4 zero4 = { 0.f, 0.f, 0.f, 0.f };

  __syncthreads();

  int lrow[4];
#pragma unroll
  for (int r = 0; r < 4; ++r) lrow[r] = lastL[q * 4 + r];

  const int srow = (tid >> 4) & 15, scol = tid & 15;   // staging/head mapping (tid<256)
  const float* histrow = hist + (long)(b0 + srow) * 1024 + scol;

  for (int t = 0; t < 64; ++t) {
    // ---- stage hist features, decay, mask (first 4 waves) ----
    if (tid < 256) {
      float v = histrow[t * 16];
      A0[srow][scol] = (__bf16)v;
      if (scol == 5)
        decayL[srow] = __fdividef(1.f, __logf(2.7182818284590452f + fmaxf(v, 0.f)));
      if (scol == 0) maskL[srow] = hmask[(b0 + srow) * 64 + t];
    }
    __syncthreads();   // (1)

    float drow[4], mrow[4];
#pragma unroll
    for (int r = 0; r < 4; ++r) { drow[r] = decayL[q * 4 + r]; mrow[r] = maskL[q * 4 + r]; }

    // ---- layer 0: z = [hist|0|h0] @ [Wfold;0;Uh0] (K=160) ----
    f32x4 acc[3];
#pragma unroll
    for (int g = 0; g < 3; ++g) acc[g] = zero4;
#pragma unroll
    for (int kk = 0; kk < 5; ++kk) {
      bf16x8 a = *(const bf16x8*)&A0[c16][kk * 32 + q8];
#pragma unroll
      for (int g = 0; g < 3; ++g) {
        bf16x8 b = *(const bf16x8*)(BT0 + offZ0[g] + kk * 32);
        acc[g] = mfma16(a, b, acc[g]);
      }
    }
    float htl[4], otl[4];
#pragma unroll
    for (int r = 0; r < 4; ++r) {
      float zi = acc[0][r] + bz0r[0];
      float zo = acc[1][r] + bz0r[1];
      float zc = acc[2][r] + bz0r[2];
      float ht = tanhfast(zc) + sigmf(zi);
      htl[r] = ht;
      otl[r] = sigmf(zo);
      Atmp[q * 4 + r][nc] = (__bf16)ht;
    }
    __syncthreads();   // (2)

    // ---- layer 0: h_short = tanh(h_tilde @ Wd0 + bd0), state update ----
    f32x4 accd = zero4;
#pragma unroll
    for (int kk = 0; kk < 4; ++kk) {
      bf16x8 a = *(const bf16x8*)&Atmp[c16][kk * 32 + q8];
      accd = mfma16(a, bwd0[kk], accd);
    }
#pragma unroll
    for (int r = 0; r < 4; ++r) {
      float hs    = tanhfast(accd[r] + bd0r);
      float dgate = sigmf(drow[r] * wt0r + bt0r);
      float hstar = htl[r] + hs * (dgate - 1.f);
      float cn    = tanhfast(hstar + otl[r] * c0r[r]);
      float hn    = otl[r] * tanhfast(cn);
      float m     = mrow[r];
      float hl    = m * hn + (1.f - m) * h0r[r];
      float cl    = m * cn + (1.f - m) * c0r[r];
      h0r[r] = hl; c0r[r] = cl;
      __bf16 hb = (__bf16)hl;
      int row = q * 4 + r;
      A0[row][32 + nc] = hb;   // next step's layer-0 recurrent input
      A1[row][nc]      = hb;   // this step's layer-1 feed-forward input
    }
    __syncthreads();   // (3)

    // ---- layer 1: z = [h0_new|h1] @ [Wx1;Uh1] (K=256) ----
#pragma unroll
    for (int g = 0; g < 3; ++g) acc[g] = zero4;
#pragma unroll
    for (int kk = 0; kk < 8; ++kk) {
      bf16x8 a = *(const bf16x8*)&A1[c16][kk * 32 + q8];
#pragma unroll
      for (int g = 0; g < 3; ++g) {
        bf16x8 b = *(const bf16x8*)(BT1 + offZ1[g] + kk * 32);
        acc[g] = mfma16(a, b, acc[g]);
      }
    }
#pragma unroll
    for (int r = 0; r < 4; ++r) {
      float zi = acc[0][r] + bz1r[0];
      float zo = acc[1][r] + bz1r[1];
      float zc = acc[2][r] + bz1r[2];
      float ht = tanhfast(zc) + sigmf(zi);
      htl[r] = ht;
      otl[r] = sigmf(zo);
      Atmp[q * 4 + r][nc] = (__bf16)ht;
    }
    __syncthreads();   // (4)

    // ---- layer 1: Wd1 + state update + capture encoded at t==last ----
    accd = zero4;
#pragma unroll
    for (int kk = 0; kk < 4; ++kk) {
      bf16x8 a = *(const bf16x8*)&Atmp[c16][kk * 32 + q8];
      accd = mfma16(a, bwd1[kk], accd);
    }
#pragma unroll
    for (int r = 0; r < 4; ++r) {
      float hs    = tanhfast(accd[r] + bd1r);
      float dgate = sigmf(drow[r] * wt1r + bt1r);
      float hstar = htl[r] + hs * (dgate - 1.f);
      float cn    = tanhfast(hstar + otl[r] * c1r[r]);
      float hn    = otl[r] * tanhfast(cn);
      float m     = mrow[r];
      float hl    = m * hn + (1.f - m) * h1r[r];
      float cl    = m * cn + (1.f - m) * c1r[r];
      h1r[r] = hl; c1r[r] = cl;
      A1[q * 4 + r][128 + nc] = (__bf16)hl;
      if (t == lrow[r]) encr[r] = hl * m;   // encoded = h1_l * mask
    }
    // no barrier: next-iter readers of A0/A1 writes are behind barriers (1)-(3)
  }

  __syncthreads();

  // ---- decoder head: state = [hist[b,last,:16] | enc128]; LN; FC-ReLU-FC ----
  if (tid < 256)
    stateL[srow][scol] = hist[((long)(b0 + srow) * 64 + lastL[srow]) * 16 + scol];
#pragma unroll
  for (int r = 0; r < 4; ++r)
    stateL[q * 4 + r][16 + nc] = encr[r];
  __syncthreads();

  if (tid < 256) {
    float sm = 0.f, sq = 0.f;
    for (int k = scol; k < 144; k += 16) {
      float v = stateL[srow][k];
      sm += v; sq += v * v;
    }
    redS[srow][scol] = sm; redQ[srow][scol] = sq;
  }
  __syncthreads();
  if (tid < 16) {
    float sm = 0.f, sq = 0.f;
    for (int s2 = 0; s2 < 16; ++s2) { sm += redS[tid][s2]; sq += redQ[tid][s2]; }
    float mu  = sm * (1.f / 144.f);
    float var = sq * (1.f / 144.f) - mu * mu;
    decayL[tid] = mu;                       // reuse buffers: mu
    maskL[tid]  = rsqrtf(var + 1e-5f);      // rstd
  }
  __syncthreads();
  if (tid < 256) {
    float mu = decayL[srow], rs = maskL[srow];
    for (int k = scol; k < 144; k += 16)
      stateL[srow][k] = (stateL[srow][k] - mu) * rs * lng[k] + lnb[k];
  }
  __syncthreads();
  if (tid < 256) {
    float accw[8];
#pragma unroll
    for (int o = 0; o < 8; ++o) accw[o] = b1[scol + 16 * o];
    for (int k = 0; k < 144; ++k) {
      float sv = stateL[srow][k];
      const float* w = W1 + k * 128 + scol;
#pragma unroll
      for (int o = 0; o < 8; ++o) accw[o] += sv * w[16 * o];
    }
#pragma unroll
    for (int o = 0; o < 8; ++o) a1L[srow][scol + 16 * o] = fmaxf(accw[o], 0.f);
  }
  __syncthreads();
  // FC2: 16 rows x 60 cols = 960 outputs per block, block-stride over 512 threads.
  for (int e = tid; e < 960; e += 512) {
    int row = e / 60, j = e - row * 60;
    float accv = b2[j];
    for (int k = 0; k < 128; ++k) accv += a1L[row][k] * W2[k * 60 + j];
    accv = (accv != accv) ? 0.f : fminf(fmaxf(accv, -1e4f), 1e4f);  // nan_to_num
    out[(b0 + row) * 60 + j] = accv;
  }
}

extern "C" void kernel_launch(void* const* d_in, const int* in_sizes, int n_in,
                              void* d_out, int out_size, void* d_ws, size_t ws_size,
                              hipStream_t stream) {
  const float* hist  = (const float*)d_in[0];
  const float* hmask = (const float*)d_in[1];
  const float* Wp    = (const float*)d_in[2];
  const float* bp    = (const float*)d_in[3];
  const float* Wx    = (const float*)d_in[4];
  const float* bx    = (const float*)d_in[5];
  const float* Uh    = (const float*)d_in[6];
  const float* Wd    = (const float*)d_in[7];
  const float* bd    = (const float*)d_in[8];
  const float* Wt    = (const float*)d_in[9];
  const float* bt    = (const float*)d_in[10];
  const float* lng   = (const float*)d_in[11];
  const float* lnb   = (const float*)d_in[12];
  const float* W1    = (const float*)d_in[13];
  const float* b1    = (const float*)d_in[14];
  const float* W2    = (const float*)d_in[15];
  const float* b2    = (const float*)d_in[16];
  float* out = (float*)d_out;

  char* ws = (char*)d_ws;
  __bf16* BT0  = (__bf16*)ws;
  __bf16* BWd0 = (__bf16*)(ws + OFF_BWD0);
  __bf16* BT1  = (__bf16*)(ws + OFF_BT1);
  __bf16* BWd1 = (__bf16*)(ws + OFF_BWD1);
  float*  bz0  = (float*)(ws + OFF_BZ0);

  tlstm_fold<<<26, 256, 0, stream>>>(Wp, bp, Wx, bx, BT0, bz0);
  tlstm_pack<<<704, 256, 0, stream>>>(Wx, Uh, Wd, BT0, BWd0, BT1, BWd1);
  tlstm_main<<<256, 512, 0, stream>>>(hist, hmask, BT0, BWd0, BT1, BWd1, bz0, bx,
                                      bd, Wt, bt, lng, lnb, W1, b1, W2, b2, out);
}

// Round 4
// 464.497 us; speedup vs baseline: 1.2841x; 1.1403x over previous
//
#include <hip/hip_runtime.h>
#include <hip/hip_bf16.h>

// TLSTM forecaster, persistent-block design. R4: all weights on-chip.
//  - BT0 (L0 gate weights, 129KB) lives in LDS (padded stride 168 -> uniform
//    8-accesses/bank for wave64 b128 reads).
//  - BT1 (L1 gate weights) + BWd0/1 hoisted to VGPRs (96+32 regs; grid=1
//    block/CU caps occupancy at 8 waves regardless, so VGPRs are free).
//  - Barrier (1) removed: hist feeds a separate K=32 MFMA from a ping-pong
//    Ahist[2] tile staged one step ahead; 3 barriers/step.
// B=4096, L=64, D=16, H=128, NL=2, FUT*MD=60, HEAD_IN=144.
// grid=256 blocks x 512 thr; block owns 16 batch rows; wave owns 16 N-cols.
// Gate order [i, o, c] (reference's f-gate is dead code).
//
// MFMA 16x16x32 bf16 layouts:
//   A[m=lane&15][k=(lane>>4)*8+j]   B[k][n=lane&15] (packed BT[n][k])
//   D[row=(lane>>4)*4+r][col=lane&15]

typedef __bf16 bf16x8 __attribute__((ext_vector_type(8)));
typedef float  f32x4  __attribute__((ext_vector_type(4)));

__device__ __forceinline__ f32x4 mfma16(bf16x8 a, bf16x8 b, f32x4 c) {
  return __builtin_amdgcn_mfma_f32_16x16x32_bf16(a, b, c, 0, 0, 0);
}
__device__ __forceinline__ float sigmf(float x) {
  return __fdividef(1.f, 1.f + __expf(-x));
}
__device__ __forceinline__ float tanhfast(float x) {
  return 1.f - __fdividef(2.f, 1.f + __expf(2.f * x));
}

// ---------------- ws layout (bytes) ----------------
// BT0p : [384][168] bf16 @ 0        (k 0..15 = Wp@Wx0 fold, 16..31 zeros, 32..159 Uh0)
// BWd0 : [128][128] bf16 @ 129024
// BT1  : [384][256] bf16 @ 161792   (k 0..127 = Wx1, 128..255 = Uh1)
// BWd1 : [128][128] bf16 @ 358400
// bz0  : [384] f32       @ 391168
#define OFF_BWD0 129024
#define OFF_BT1  161792
#define OFF_BWD1 358400
#define OFF_BZ0  391168

// ---------------- dynamic LDS layout (bytes) ----------------
#define S_WB0   0        // [384][168] bf16 = 129024
#define S_AH    129024   // Ahist[2][16][40] bf16 = 2560 (cols 16..31 zero)
#define S_A0H   131584   // [16][136] bf16 = 4352  (h0)
#define S_A1    135936   // [16][264] bf16 = 8448  ([h0_new | h1])
#define S_ATMP  144384   // [16][136] bf16 = 4352  (h_tilde)
#define S_DEC   148736   // [2][16] f32
#define S_MASK  148864   // [2][16] f32
#define S_LAST  148992   // [16] int
#define S_TOTAL 149056
// head-stage aliases (over WB0; all weight reads done by then):
#define S_STATE 0        // [16][144] f32 = 9216
#define S_A1L   9216     // [16][128] f32 = 8192
#define S_REDS  17408    // [16][16] f32
#define S_REDQ  18432    // [16][16] f32

__global__ void tlstm_fold(const float* __restrict__ Wp, const float* __restrict__ bp,
                           const float* __restrict__ Wx, const float* __restrict__ bx,
                           __bf16* __restrict__ BT0, float* __restrict__ bz0) {
  int idx = blockIdx.x * 256 + threadIdx.x;
  if (idx >= 384 * 17) return;
  int n = idx / 17, kk = idx % 17;
  int g = n >> 7, npr = n & 127, gs = g + 1;               // src gates 1,2,3 = i,o,c
  const float* wxcol = Wx + (gs * 128) * 128 + npr;        // Wx[0][gs][h][npr]
  if (kk < 16) {
    const float* wprow = Wp + kk * 128;
    float s = 0.f;
    for (int h = 0; h < 128; ++h) s += wprow[h] * wxcol[h * 128];
    BT0[n * 168 + kk] = (__bf16)s;
  } else {
    float s = bx[gs * 128 + npr];
    for (int h = 0; h < 128; ++h) s += bp[h] * wxcol[h * 128];
    bz0[n] = s;
    for (int k2 = 16; k2 < 32; ++k2) BT0[n * 168 + k2] = (__bf16)0.f;  // zero K-pad
  }
}

__global__ void tlstm_pack(const float* __restrict__ Wx, const float* __restrict__ Uh,
                           const float* __restrict__ Wd,
                           __bf16* __restrict__ BT0, __bf16* __restrict__ BWd0,
                           __bf16* __restrict__ BT1, __bf16* __restrict__ BWd1) {
  int e = blockIdx.x * 256 + threadIdx.x;
  if (e < 49152) {                                  // BT0 Uh0 region
    int n = e >> 7, k = e & 127, npr = n & 127, gs = (n >> 7) + 1;
    BT0[n * 168 + 32 + k] = (__bf16)Uh[(gs * 128 + k) * 128 + npr];
  } else if (e < 65536) {                           // BWd0
    int e2 = e - 49152; int n = e2 >> 7, k = e2 & 127;
    BWd0[n * 128 + k] = (__bf16)Wd[k * 128 + n];
  } else if (e < 163840) {                          // BT1 = [Wx1 ; Uh1]
    int e2 = e - 65536; int n = e2 >> 8, k = e2 & 255;
    int npr = n & 127, gs = (n >> 7) + 1;
    float v = (k < 128) ? Wx[((4 + gs) * 128 + k) * 128 + npr]
                        : Uh[((4 + gs) * 128 + (k - 128)) * 128 + npr];
    BT1[n * 256 + k] = (__bf16)v;
  } else if (e < 180224) {                          // BWd1
    int e2 = e - 163840; int n = e2 >> 7, k = e2 & 127;
    BWd1[n * 128 + k] = (__bf16)Wd[(128 + k) * 128 + n];
  }
}

__global__ __launch_bounds__(512, 1) void tlstm_main(
    const float* __restrict__ hist, const float* __restrict__ hmask,
    const __bf16* __restrict__ BT0, const __bf16* __restrict__ BWd0,
    const __bf16* __restrict__ BT1, const __bf16* __restrict__ BWd1,
    const float* __restrict__ bz0, const float* __restrict__ bx,
    const float* __restrict__ bd, const float* __restrict__ Wt,
    const float* __restrict__ bt, const float* __restrict__ lng,
    const float* __restrict__ lnb, const float* __restrict__ W1,
    const float* __restrict__ b1, const float* __restrict__ W2,
    const float* __restrict__ b2, float* __restrict__ out) {
  extern __shared__ __align__(16) char smem[];
  __bf16* WB0 = (__bf16*)(smem + S_WB0);
  __bf16 (*AH)[16][40]  = (__bf16(*)[16][40])(smem + S_AH);
  __bf16 (*A0H)[136]    = (__bf16(*)[136])(smem + S_A0H);
  __bf16 (*A1)[264]     = (__bf16(*)[264])(smem + S_A1);
  __bf16 (*ATMP)[136]   = (__bf16(*)[136])(smem + S_ATMP);
  float (*decayL)[16]   = (float(*)[16])(smem + S_DEC);
  float (*maskL)[16]    = (float(*)[16])(smem + S_MASK);
  int*   lastL          = (int*)(smem + S_LAST);
  float (*stateL)[144]  = (float(*)[144])(smem + S_STATE);
  float (*a1L)[128]     = (float(*)[128])(smem + S_A1L);
  float (*redS)[16]     = (float(*)[16])(smem + S_REDS);
  float (*redQ)[16]     = (float(*)[16])(smem + S_REDQ);

  const int tid  = threadIdx.x;
  const int wave = tid >> 6;         // 0..7
  const int lane = tid & 63;
  const int q    = lane >> 4;
  const int c16  = lane & 15;
  const int q8   = q * 8;
  const int b0   = blockIdx.x * 16;
  const int nc   = wave * 16 + c16;  // owned N-column (0..127)

  // ---- one-time: copy BT0 into LDS, zero tiles, lastL ----
  for (int i = tid * 8; i < 64512; i += 4096)
    *(bf16x8*)(WB0 + i) = *(const bf16x8*)(BT0 + i);
  {
    __bf16* z = (__bf16*)(smem + S_AH);
    for (int i = tid; i < 9856; i += 512) z[i] = (__bf16)0.f;  // AH+A0H+A1+ATMP
  }
  if (tid < 16) {
    float s = 0.f;
    for (int t = 0; t < 64; ++t) s += hmask[(b0 + tid) * 64 + t];
    s = fminf(fmaxf(s, 1.f), 64.f);
    lastL[tid] = (int)s - 1;
  }

  // per-wave column constants
  float bz0r[3], bz1r[3];
#pragma unroll
  for (int g = 0; g < 3; ++g) {
    bz0r[g] = bz0[g * 128 + nc];
    bz1r[g] = bx[(5 + g) * 128 + nc];
  }
  const float bd0r = bd[nc],      bd1r = bd[128 + nc];
  const float wt0r = Wt[nc],      wt1r = Wt[128 + nc];
  const float bt0r = bt[nc],      bt1r = bt[128 + nc];

  int offZ0[3];
#pragma unroll
  for (int g = 0; g < 3; ++g) offZ0[g] = (g * 128 + nc) * 168;

  // hoist BT1 + BWd fragments into registers (constant over t)
  bf16x8 wt1f[24], bwd0[4], bwd1[4];
#pragma unroll
  for (int g = 0; g < 3; ++g)
#pragma unroll
    for (int kk = 0; kk < 8; ++kk)
      wt1f[g * 8 + kk] = *(const bf16x8*)(BT1 + (g * 128 + nc) * 256 + kk * 32 + q8);
#pragma unroll
  for (int kk = 0; kk < 4; ++kk) {
    bwd0[kk] = *(const bf16x8*)(BWd0 + nc * 128 + q8 + kk * 32);
    bwd1[kk] = *(const bf16x8*)(BWd1 + nc * 128 + q8 + kk * 32);
  }

  float h0r[4] = {}, c0r[4] = {}, h1r[4] = {}, c1r[4] = {}, encr[4] = {};

  __syncthreads();   // zero-init / copy complete

  int lrow[4];
#pragma unroll
  for (int r = 0; r < 4; ++r) lrow[r] = lastL[q * 4 + r];

  const int srow = (tid >> 4) & 15, scol = tid & 15;   // staging/head map (tid<256)
  const float* histrow = hist + (long)(b0 + srow) * 1024 + scol;
  const float* hmrow   = hmask + (long)(b0 + srow) * 64;

  // stage t=0 into slot 0; prefetch t=1 into regs
  float hv = 0.f, mv = 0.f;
  if (tid < 256) {
    float v0 = histrow[0];
    AH[0][srow][scol] = (__bf16)v0;
    if (scol == 5)
      decayL[0][srow] = __fdividef(1.f, __logf(2.7182818284590452f + fmaxf(v0, 0.f)));
    if (scol == 0) maskL[0][srow] = hmrow[0];
    hv = histrow[16];
    mv = hmrow[1];
  }
  __syncthreads();   // staging slot 0 visible

  for (int t = 0; t < 64; ++t) {
    const int p = t & 1, pn = p ^ 1;
    // ---- stage t+1 into slot pn (readers of pn are >=3 barriers away) ----
    if (tid < 256 && t < 63) {
      AH[pn][srow][scol] = (__bf16)hv;
      if (scol == 5)
        decayL[pn][srow] = __fdividef(1.f, __logf(2.7182818284590452f + fmaxf(hv, 0.f)));
      if (scol == 0) maskL[pn][srow] = mv;
      if (t < 62) { hv = histrow[(t + 2) * 16]; mv = hmrow[t + 2]; }
    }

    float drow[4], mrow[4];
#pragma unroll
    for (int r = 0; r < 4; ++r) {
      drow[r] = decayL[p][q * 4 + r];
      mrow[r] = maskL[p][q * 4 + r];
    }

    // ---- layer 0 gates: z = hist@Wfold (K=32, ping-pong) + h0@Uh0 (K=128) ----
    f32x4 acc[3];
#pragma unroll
    for (int g = 0; g < 3; ++g) acc[g] = (f32x4){bz0r[g], bz0r[g], bz0r[g], bz0r[g]};
    {
      bf16x8 a = *(const bf16x8*)&AH[p][c16][q8];
#pragma unroll
      for (int g = 0; g < 3; ++g)
        acc[g] = mfma16(a, *(const bf16x8*)(WB0 + offZ0[g] + q8), acc[g]);
    }
#pragma unroll
    for (int kk = 0; kk < 4; ++kk) {
      bf16x8 a = *(const bf16x8*)&A0H[c16][kk * 32 + q8];
#pragma unroll
      for (int g = 0; g < 3; ++g)
        acc[g] = mfma16(a, *(const bf16x8*)(WB0 + offZ0[g] + 32 + kk * 32 + q8), acc[g]);
    }
    float htl[4], otl[4];
#pragma unroll
    for (int r = 0; r < 4; ++r) {
      float ht = tanhfast(acc[2][r]) + sigmf(acc[0][r]);
      htl[r] = ht;
      otl[r] = sigmf(acc[1][r]);
      ATMP[q * 4 + r][nc] = (__bf16)ht;
    }
    __syncthreads();   // (2)

    // ---- layer 0 Wd + state update ----
    f32x4 accd = (f32x4){bd0r, bd0r, bd0r, bd0r};
#pragma unroll
    for (int kk = 0; kk < 4; ++kk) {
      bf16x8 a = *(const bf16x8*)&ATMP[c16][kk * 32 + q8];
      accd = mfma16(a, bwd0[kk], accd);
    }
#pragma unroll
    for (int r = 0; r < 4; ++r) {
      float hs    = tanhfast(accd[r]);
      float dgate = sigmf(drow[r] * wt0r + bt0r);
      float hstar = htl[r] + hs * (dgate - 1.f);
      float cn    = tanhfast(hstar + otl[r] * c0r[r]);
      float hn    = otl[r] * tanhfast(cn);
      float m     = mrow[r];
      float hl    = m * hn + (1.f - m) * h0r[r];
      float cl    = m * cn + (1.f - m) * c0r[r];
      h0r[r] = hl; c0r[r] = cl;
      __bf16 hb = (__bf16)hl;
      int row = q * 4 + r;
      A0H[row][nc] = hb;   // next step's L0 recurrent input
      A1[row][nc]  = hb;   // this step's L1 feed-forward input
    }
    __syncthreads();   // (3)

    // ---- layer 1 gates: z = [h0_new|h1] @ [Wx1;Uh1] (K=256, B in regs) ----
#pragma unroll
    for (int g = 0; g < 3; ++g) acc[g] = (f32x4){bz1r[g], bz1r[g], bz1r[g], bz1r[g]};
#pragma unroll
    for (int kk = 0; kk < 8; ++kk) {
      bf16x8 a = *(const bf16x8*)&A1[c16][kk * 32 + q8];
#pragma unroll
      for (int g = 0; g < 3; ++g)
        acc[g] = mfma16(a, wt1f[g * 8 + kk], acc[g]);
    }
#pragma unroll
    for (int r = 0; r < 4; ++r) {
      float ht = tanhfast(acc[2][r]) + sigmf(acc[0][r]);
      htl[r] = ht;
      otl[r] = sigmf(acc[1][r]);
      ATMP[q * 4 + r][nc] = (__bf16)ht;
    }
    __syncthreads();   // (4)

    // ---- layer 1 Wd + state update + capture encoded at t==last ----
    accd = (f32x4){bd1r, bd1r, bd1r, bd1r};
#pragma unroll
    for (int kk = 0; kk < 4; ++kk) {
      bf16x8 a = *(const bf16x8*)&ATMP[c16][kk * 32 + q8];
      accd = mfma16(a, bwd1[kk], accd);
    }
#pragma unroll
    for (int r = 0; r < 4; ++r) {
      float hs    = tanhfast(accd[r]);
      float dgate = sigmf(drow[r] * wt1r + bt1r);
      float hstar = htl[r] + hs * (dgate - 1.f);
      float cn    = tanhfast(hstar + otl[r] * c1r[r]);
      float hn    = otl[r] * tanhfast(cn);
      float m     = mrow[r];
      float hl    = m * hn + (1.f - m) * h1r[r];
      float cl    = m * cn + (1.f - m) * c1r[r];
      h1r[r] = hl; c1r[r] = cl;
      A1[q * 4 + r][128 + nc] = (__bf16)hl;
      if (t == lrow[r]) encr[r] = hl * m;
    }
    // no barrier: next-iter readers are behind (2)/(3)/(4)
  }

  __syncthreads();   // all WB0 reads done; safe to alias head buffers

  // ---- decoder head: state = [hist[b,last,:16] | enc128]; LN; FC-ReLU-FC ----
  if (tid < 256)
    stateL[srow][scol] = hist[((long)(b0 + srow) * 64 + lastL[srow]) * 16 + scol];
#pragma unroll
  for (int r = 0; r < 4; ++r)
    stateL[q * 4 + r][16 + nc] = encr[r];
  __syncthreads();

  if (tid < 256) {
    float sm = 0.f, sq = 0.f;
    for (int k = scol; k < 144; k += 16) {
      float v = stateL[srow][k];
      sm += v; sq += v * v;
    }
    redS[srow][scol] = sm; redQ[srow][scol] = sq;
  }
  __syncthreads();
  if (tid < 16) {
    float sm = 0.f, sq = 0.f;
    for (int s2 = 0; s2 < 16; ++s2) { sm += redS[tid][s2]; sq += redQ[tid][s2]; }
    float mu  = sm * (1.f / 144.f);
    float var = sq * (1.f / 144.f) - mu * mu;
    decayL[0][tid] = mu;
    maskL[0][tid]  = rsqrtf(var + 1e-5f);
  }
  __syncthreads();
  if (tid < 256) {
    float mu = decayL[0][srow], rs = maskL[0][srow];
    for (int k = scol; k < 144; k += 16)
      stateL[srow][k] = (stateL[srow][k] - mu) * rs * lng[k] + lnb[k];
  }
  __syncthreads();
  if (tid < 256) {
    float accw[8];
#pragma unroll
    for (int o = 0; o < 8; ++o) accw[o] = b1[scol + 16 * o];
    for (int k = 0; k < 144; ++k) {
      float sv = stateL[srow][k];
      const float* w = W1 + k * 128 + scol;
#pragma unroll
      for (int o = 0; o < 8; ++o) accw[o] += sv * w[16 * o];
    }
#pragma unroll
    for (int o = 0; o < 8; ++o) a1L[srow][scol + 16 * o] = fmaxf(accw[o], 0.f);
  }
  __syncthreads();
  for (int e = tid; e < 960; e += 512) {
    int row = e / 60, j = e - row * 60;
    float accv = b2[j];
    for (int k = 0; k < 128; ++k) accv += a1L[row][k] * W2[k * 60 + j];
    accv = (accv != accv) ? 0.f : fminf(fmaxf(accv, -1e4f), 1e4f);  // nan_to_num
    out[(b0 + row) * 60 + j] = accv;
  }
}

extern "C" void kernel_launch(void* const* d_in, const int* in_sizes, int n_in,
                              void* d_out, int out_size, void* d_ws, size_t ws_size,
                              hipStream_t stream) {
  const float* hist  = (const float*)d_in[0];
  const float* hmask = (const float*)d_in[1];
  const float* Wp    = (const float*)d_in[2];
  const float* bp    = (const float*)d_in[3];
  const float* Wx    = (const float*)d_in[4];
  const float* bx    = (const float*)d_in[5];
  const float* Uh    = (const float*)d_in[6];
  const float* Wd    = (const float*)d_in[7];
  const float* bd    = (const float*)d_in[8];
  const float* Wt    = (const float*)d_in[9];
  const float* bt    = (const float*)d_in[10];
  const float* lng   = (const float*)d_in[11];
  const float* lnb   = (const float*)d_in[12];
  const float* W1    = (const float*)d_in[13];
  const float* b1    = (const float*)d_in[14];
  const float* W2    = (const float*)d_in[15];
  const float* b2    = (const float*)d_in[16];
  float* out = (float*)d_out;

  char* ws = (char*)d_ws;
  __bf16* BT0  = (__bf16*)ws;
  __bf16* BWd0 = (__bf16*)(ws + OFF_BWD0);
  __bf16* BT1  = (__bf16*)(ws + OFF_BT1);
  __bf16* BWd1 = (__bf16*)(ws + OFF_BWD1);
  float*  bz0  = (float*)(ws + OFF_BZ0);

  hipFuncSetAttribute((const void*)tlstm_main,
                      hipFuncAttributeMaxDynamicSharedMemorySize, S_TOTAL);

  tlstm_fold<<<26, 256, 0, stream>>>(Wp, bp, Wx, bx, BT0, bz0);
  tlstm_pack<<<704, 256, 0, stream>>>(Wx, Uh, Wd, BT0, BWd0, BT1, BWd1);
  tlstm_main<<<256, 512, S_TOTAL, stream>>>(hist, hmask, BT0, BWd0, BT1, BWd1,
                                            bz0, bx, bd, Wt, bt, lng, lnb,
                                            W1, b1, W2, b2, out);
}